// Round 3
// baseline (134.401 us; speedup 1.0000x reference)
//
#include <hip/hip_runtime.h>

#define B_ 16
#define N_ 128
#define A_ 32
#define O_ 64
#define VD_ 768
#define H_ 1024

typedef short s16x8 __attribute__((ext_vector_type(8)));
typedef short s16x4 __attribute__((ext_vector_type(4)));
typedef float f32x4 __attribute__((ext_vector_type(4)));

#define MFMA(a, b, c) __builtin_amdgcn_mfma_f32_16x16x32_bf16(a, b, c, 0, 0, 0)

__device__ __forceinline__ short bf_hi(float x) {
    return (short)(__float_as_uint(x) >> 16);
}
__device__ __forceinline__ short bf_lo(float x) {
    float r = x - __uint_as_float(__float_as_uint(x) & 0xffff0000u);
    return (short)(__float_as_uint(r) >> 16);
}
__device__ __forceinline__ void cvt8(const float4& f0, const float4& f1,
                                     s16x8& hi, s16x8& lo) {
    const float ff[8] = {f0.x, f0.y, f0.z, f0.w, f1.x, f1.y, f1.z, f1.w};
    #pragma unroll
    for (int e = 0; e < 8; ++e) { hi[e] = bf_hi(ff[e]); lo[e] = bf_lo(ff[e]); }
}

__device__ __forceinline__ void gload16(const void* g, void* l) {
    __builtin_amdgcn_global_load_lds(
        (const __attribute__((address_space(1))) void*)g,
        (__attribute__((address_space(3))) void*)l, 16, 0, 0);
}

// ---------------------------------------------------------------------------
// Pre-split f32 -> (hi bf16, lo bf16) for obj, q, vw, qw.
// Block = 1024 float4s (4096 floats). Segments: obj 192, q 384, vw 192, qw 192.
// ---------------------------------------------------------------------------
__global__ __launch_bounds__(256)
void cvt_split(const float* __restrict__ obj, const float* __restrict__ q,
               const float* __restrict__ vw, const float* __restrict__ qw,
               short* __restrict__ objh, short* __restrict__ objl,
               short* __restrict__ qh, short* __restrict__ ql,
               short* __restrict__ vwh, short* __restrict__ vwl,
               short* __restrict__ qwh, short* __restrict__ qwl)
{
    const int bid = blockIdx.x;
    const float* src; short* hi; short* lo; int base4;
    if (bid < 192)      { src = obj; hi = objh; lo = objl; base4 = bid * 1024; }
    else if (bid < 576) { src = q;   hi = qh;   lo = ql;   base4 = (bid - 192) * 1024; }
    else if (bid < 768) { src = vw;  hi = vwh;  lo = vwl;  base4 = (bid - 576) * 1024; }
    else                { src = qw;  hi = qwh;  lo = qwl;  base4 = (bid - 768) * 1024; }
    #pragma unroll
    for (int it = 0; it < 4; ++it) {
        const size_t f4 = (size_t)base4 + it * 256 + threadIdx.x;
        const float4 v = *(const float4*)(src + f4 * 4);
        const float ff[4] = {v.x, v.y, v.z, v.w};
        s16x4 h4, l4;
        #pragma unroll
        for (int e = 0; e < 4; ++e) { h4[e] = bf_hi(ff[e]); l4[e] = bf_lo(ff[e]); }
        *(s16x4*)(hi + f4 * 4) = h4;
        *(s16x4*)(lo + f4 * 4) = l4;
    }
}

// ---------------------------------------------------------------------------
// Unified split-bf16 NT GEMM on pre-split operands, staged via global_load_lds
// (pre-swizzled global source, linear LDS dest, swizzled ds_read).
// Blocks [0,256):  W[b][h][o] (transposed split-bf16) = obj[b*64+o,:] . vw[h,:]
// Blocks [256,768): u[m][h] f32 = relu(q[m,:] . qw[h,:] + qb[h]) * lw[h]
// ---------------------------------------------------------------------------
__global__ __launch_bounds__(256)
void gemm_split(const short* __restrict__ objh, const short* __restrict__ objl,
                const short* __restrict__ qh, const short* __restrict__ ql,
                const short* __restrict__ vwh, const short* __restrict__ vwl,
                const short* __restrict__ qwh, const short* __restrict__ qwl,
                const float* __restrict__ qb, const float* __restrict__ lwp,
                short* __restrict__ Wth, short* __restrict__ Wtl,
                float* __restrict__ ub)
{
    __shared__ __align__(16) short lds[4 * 4096];   // Xh | Xl | Bh | Bl (64x64 each)
    const int bid = blockIdx.x;
    const bool isA = bid < 256;
    const int lb_ = isA ? bid : bid - 256;
    const int r0 = (lb_ >> 4) * 64;
    const int h0 = (lb_ & 15) * 64;
    const short* Xh = isA ? objh : qh;
    const short* Xl = isA ? objl : ql;
    const short* Bh = isA ? vwh : qwh;
    const short* Bl = isA ? vwl : qwl;

    const int tid = threadIdx.x;
    const int w = tid >> 6, l = tid & 63;
    const int wm = (w >> 1) * 32, wn = (w & 1) * 32;
    const int g = l >> 4, c16 = l & 15;

    // staging: unit = t*256 + tid; row = unit>>3; source col unit u = (unit&7)^(row&7)
    const int row0 = tid >> 3, u0 = (tid & 7) ^ (row0 & 7);
    const int unit1 = 256 + tid;
    const int row1 = unit1 >> 3, u1 = (unit1 & 7) ^ (row1 & 7);
    const short* pXh = Xh + (size_t)r0 * VD_;
    const short* pXl = Xl + (size_t)r0 * VD_;
    const short* pBh = Bh + (size_t)h0 * VD_;
    const short* pBl = Bl + (size_t)h0 * VD_;
    int go0 = row0 * VD_ + u0 * 8;
    int go1 = row1 * VD_ + u1 * 8;
    short* const d0 = &lds[w * 512];          // + a*4096 (+2048 for t=1)

    f32x4 acc[2][2] = {};

    for (int c = 0; c < VD_ / 64; ++c) {
        __syncthreads();
        gload16(pXh + go0, d0);
        gload16(pXh + go1, d0 + 2048);
        gload16(pXl + go0, d0 + 4096);
        gload16(pXl + go1, d0 + 4096 + 2048);
        gload16(pBh + go0, d0 + 8192);
        gload16(pBh + go1, d0 + 8192 + 2048);
        gload16(pBl + go0, d0 + 12288);
        gload16(pBl + go1, d0 + 12288 + 2048);
        go0 += 64; go1 += 64;
        __syncthreads();
        #pragma unroll
        for (int s = 0; s < 2; ++s) {
            s16x8 ah[2], al[2], bh2[2], bl2[2];
            #pragma unroll
            for (int i = 0; i < 2; ++i) {
                const int m = wm + i * 16 + c16;
                const int us = (((s * 4 + g) ^ (m & 7)) * 8);
                ah[i]  = *(const s16x8*)&lds[m * 64 + us];
                al[i]  = *(const s16x8*)&lds[4096 + m * 64 + us];
                const int n = wn + i * 16 + c16;
                const int vs = (((s * 4 + g) ^ (n & 7)) * 8);
                bh2[i] = *(const s16x8*)&lds[8192 + n * 64 + vs];
                bl2[i] = *(const s16x8*)&lds[12288 + n * 64 + vs];
            }
            #pragma unroll
            for (int i = 0; i < 2; ++i)
                #pragma unroll
                for (int j = 0; j < 2; ++j) {
                    acc[i][j] = MFMA(ah[i], bh2[j], acc[i][j]);
                    acc[i][j] = MFMA(ah[i], bl2[j], acc[i][j]);
                    acc[i][j] = MFMA(al[i], bh2[j], acc[i][j]);
                }
        }
    }

    #pragma unroll
    for (int i = 0; i < 2; ++i)
        #pragma unroll
        for (int j = 0; j < 2; ++j) {
            const int h = h0 + wn + j * 16 + c16;
            if (isA) {
                const int o = wm + i * 16 + g * 4;
                s16x4 hi4, lo4;
                #pragma unroll
                for (int r = 0; r < 4; ++r) {
                    hi4[r] = bf_hi(acc[i][j][r]);
                    lo4[r] = bf_lo(acc[i][j][r]);
                }
                const size_t dst = ((size_t)(lb_ >> 4) * H_ + h) * O_ + o;
                *(s16x4*)&Wth[dst] = hi4;
                *(s16x4*)&Wtl[dst] = lo4;
            } else {
                const float bv = qb[h], sv = lwp[h];
                #pragma unroll
                for (int r = 0; r < 4; ++r) {
                    const int m = r0 + wm + i * 16 + g * 4 + r;
                    ub[(size_t)m * H_ + h] = fmaxf(acc[i][j][r] + bv, 0.f) * sv;
                }
            }
        }
}

// ---------------------------------------------------------------------------
// Stage 1: per (b, n-pair, h-half) block computes partial logits over 512 h.
// 64 rows (2n x 32a); A-frags in registers; W fragments prefetched 1 nt ahead.
// ---------------------------------------------------------------------------
__global__ __launch_bounds__(256, 3)
void logits_part(const float* __restrict__ att1, const short* __restrict__ Wth,
                 const short* __restrict__ Wtl, const float* __restrict__ ub,
                 const float* __restrict__ vb, float* __restrict__ lgws)
{
    __shared__ __align__(16) short Ah[64 * 64], Al[64 * 64];
    __shared__ float lgp[4][64];

    const int blk = blockIdx.x;          // ((b*64+pair)*2 + half)
    const int b = blk >> 7;
    const int pair = (blk >> 1) & 63;
    const int half = blk & 1;
    const int n0 = pair * 2;
    const int tid = threadIdx.x;
    const size_t base_row = (size_t)(b * N_ + n0) * A_;

    {   // stage att1 tile as swizzled split-bf16
        const int row = tid >> 2, qq = tid & 3;
        const float* src = att1 + (base_row + row) * O_ + qq * 16;
        #pragma unroll
        for (int uu = 0; uu < 2; ++uu) {
            const float4 f0 = *(const float4*)(src + uu * 8);
            const float4 f1 = *(const float4*)(src + uu * 8 + 4);
            const int us = ((qq * 2 + uu) ^ (row & 7)) * 8;
            s16x8 hi, lo; cvt8(f0, f1, hi, lo);
            *(s16x8*)&Ah[row * 64 + us] = hi;
            *(s16x8*)&Al[row * 64 + us] = lo;
        }
    }
    __syncthreads();

    const int w = tid >> 6, l = tid & 63;
    const int g = l >> 4, c16 = l & 15;

    s16x8 ahf[4][2], alf[4][2];
    #pragma unroll
    for (int i = 0; i < 4; ++i)
        #pragma unroll
        for (int s = 0; s < 2; ++s) {
            const int m = i * 16 + c16;
            const int us = ((s * 4 + g) ^ (m & 7)) * 8;
            ahf[i][s] = *(const s16x8*)&Ah[m * 64 + us];
            alf[i][s] = *(const s16x8*)&Al[m * 64 + us];
        }

    const int hb = half * 512 + w * 128 + c16;
    const size_t wbase = ((size_t)b * H_ + hb) * O_ + g * 8;
    const float* vbp = vb + hb;
    const float* u0p = ub + (size_t)(b * N_ + n0) * H_ + hb;
    const float* u1p = u0p + H_;

#define LOADNT(NT, B0, B1, B2, B3, V0, V1, V2) do {            \
        const short* ph_ = Wth + wbase + (NT) * 1024;          \
        const short* pl_ = Wtl + wbase + (NT) * 1024;          \
        B0 = *(const s16x8*)ph_;  B1 = *(const s16x8*)(ph_ + 32); \
        B2 = *(const s16x8*)pl_;  B3 = *(const s16x8*)(pl_ + 32); \
        V0 = vbp[(NT) * 16]; V1 = u0p[(NT) * 16]; V2 = u1p[(NT) * 16]; \
    } while (0)

    s16x8 c0, c1, c2, c3; float v0, v1, v2;
    LOADNT(0, c0, c1, c2, c3, v0, v1, v2);
    f32x4 part[4] = {};

    #pragma unroll
    for (int nt = 0; nt < 8; ++nt) {
        s16x8 p0, p1, p2, p3; float y0, y1, y2;
        if (nt < 7) LOADNT(nt + 1, p0, p1, p2, p3, y0, y1, y2);
        #pragma unroll
        for (int i = 0; i < 4; ++i) {
            f32x4 acc = {};
            acc = MFMA(ahf[i][0], c0, acc);
            acc = MFMA(alf[i][0], c0, acc);
            acc = MFMA(ahf[i][0], c2, acc);
            acc = MFMA(ahf[i][1], c1, acc);
            acc = MFMA(alf[i][1], c1, acc);
            acc = MFMA(ahf[i][1], c3, acc);
            const float uu = (i < 2) ? v1 : v2;
            #pragma unroll
            for (int r = 0; r < 4; ++r)
                part[i][r] += fmaxf(acc[r] + v0, 0.f) * uu;
        }
        if (nt < 7) { c0 = p0; c1 = p1; c2 = p2; c3 = p3; v0 = y0; v1 = y1; v2 = y2; }
    }
#undef LOADNT

    #pragma unroll
    for (int i = 0; i < 4; ++i)
        #pragma unroll
        for (int r = 0; r < 4; ++r) {
            float v = part[i][r];
            v += __shfl_xor(v, 1, 64);
            v += __shfl_xor(v, 2, 64);
            v += __shfl_xor(v, 4, 64);
            v += __shfl_xor(v, 8, 64);
            if (c16 == 0) lgp[w][i * 16 + g * 4 + r] = v;
        }
    __syncthreads();

    if (tid < 64) {
        const float s = lgp[0][tid] + lgp[1][tid] + lgp[2][tid] + lgp[3][tid];
        lgws[(size_t)(blk >> 1) * 128 + half * 64 + tid] = s;
    }
}

// ---------------------------------------------------------------------------
// Stage 2: combine halves, mask, softmax, att2 @ att1. One block per n-pair.
// ---------------------------------------------------------------------------
__global__ __launch_bounds__(128)
void finish(const float* __restrict__ att1, const float* __restrict__ lgws,
            const int* __restrict__ tags, const int* __restrict__ tptr,
            const float* __restrict__ lbptr, float* __restrict__ out)
{
    __shared__ float sml[64];
    const int pg = blockIdx.x;           // 0..1023
    const int b = pg >> 6, n0 = (pg & 63) * 2;
    const int tid = threadIdx.x;
    const size_t base_row = (size_t)(b * N_ + n0) * A_;

    if (tid < 64) {
        const float tf = (float)(*tptr);
        const float lv = (lgws[(size_t)pg * 128 + tid] +
                          lgws[(size_t)pg * 128 + 64 + tid] + *lbptr) / tf;
        const int tg = tags[base_row + tid];
        sml[tid] = (tg > 0) ? lv : -1e30f;
    }
    __syncthreads();

    const int nn = tid >> 6, o = tid & 63;
    const float* lr = &sml[nn * 32];
    float m = -3.0e38f;
    #pragma unroll
    for (int a = 0; a < 32; ++a) m = fmaxf(m, lr[a]);
    float s = 0.f, accum = 0.f;
    #pragma unroll
    for (int a = 0; a < 32; ++a) {
        const float e = __expf(lr[a] - m);
        s += e;
        accum += e * att1[(base_row + nn * 32 + a) * O_ + o];
    }
    out[(size_t)(b * N_ + n0 + nn) * O_ + o] = accum / s;
}

extern "C" void kernel_launch(void* const* d_in, const int* in_sizes, int n_in,
                              void* d_out, int out_size, void* d_ws, size_t ws_size,
                              hipStream_t stream)
{
    const float* q    = (const float*)d_in[0];
    const float* att1 = (const float*)d_in[1];
    const float* obj  = (const float*)d_in[2];
    const int*   tags = (const int*)d_in[3];
    const int*   tptr = (const int*)d_in[4];
    const float* vw   = (const float*)d_in[5];
    const float* vb   = (const float*)d_in[6];
    const float* qw   = (const float*)d_in[7];
    const float* qb   = (const float*)d_in[8];
    const float* lw   = (const float*)d_in[9];
    const float* lb   = (const float*)d_in[10];
    float* out = (float*)d_out;

    float* ub   = (float*)d_ws;                         // [2048][1024] f32   8 MB
    float* lgws = ub + (size_t)B_ * N_ * H_;            // [1024][128] f32    512 KB
    short* Wth  = (short*)(lgws + 1024 * 128);          // [16][1024][64]     2 MB
    short* Wtl  = Wth + (size_t)B_ * H_ * O_;           //                    2 MB
    short* objh = Wtl + (size_t)B_ * H_ * O_;           // [1024][768]        1.5 MB
    short* objl = objh + (size_t)1024 * VD_;
    short* qh   = objl + (size_t)1024 * VD_;            // [2048][768]        3 MB
    short* ql   = qh + (size_t)2048 * VD_;
    short* vwh  = ql + (size_t)2048 * VD_;              // [1024][768]
    short* vwl  = vwh + (size_t)H_ * VD_;
    short* qwh  = vwl + (size_t)H_ * VD_;
    short* qwl  = qwh + (size_t)H_ * VD_;

    cvt_split<<<960, 256, 0, stream>>>(obj, q, vw, qw, objh, objl, qh, ql,
                                       vwh, vwl, qwh, qwl);
    gemm_split<<<768, 256, 0, stream>>>(objh, objl, qh, ql, vwh, vwl, qwh, qwl,
                                        qb, lw, Wth, Wtl, ub);
    logits_part<<<B_ * 64 * 2, 256, 0, stream>>>(att1, Wth, Wtl, ub, vb, lgws);
    finish<<<B_ * 64, 128, 0, stream>>>(att1, lgws, tags, tptr, lb, out);
}

// Round 4
// 73.553 us; speedup vs baseline: 1.8273x; 1.8273x over previous
//
#include <hip/hip_runtime.h>

#define B_ 16
#define N_ 128
#define A_ 32
#define O_ 64
#define VD_ 768
#define H_ 1024

typedef short s16x8 __attribute__((ext_vector_type(8)));
typedef short s16x4 __attribute__((ext_vector_type(4)));
typedef float f32x4 __attribute__((ext_vector_type(4)));

#define MFMA(a, b, c) __builtin_amdgcn_mfma_f32_16x16x32_bf16(a, b, c, 0, 0, 0)

__device__ __forceinline__ short bf_hi(float x) {
    return (short)(__float_as_uint(x) >> 16);
}
__device__ __forceinline__ short bf_lo(float x) {
    float r = x - __uint_as_float(__float_as_uint(x) & 0xffff0000u);
    return (short)(__float_as_uint(r) >> 16);
}
__device__ __forceinline__ void cvt8(const float4& f0, const float4& f1,
                                     s16x8& hi, s16x8& lo) {
    const float ff[8] = {f0.x, f0.y, f0.z, f0.w, f1.x, f1.y, f1.z, f1.w};
    #pragma unroll
    for (int e = 0; e < 8; ++e) { hi[e] = bf_hi(ff[e]); lo[e] = bf_lo(ff[e]); }
}

__device__ __forceinline__ void gload16(const void* g, void* l) {
    __builtin_amdgcn_global_load_lds(
        (const __attribute__((address_space(1))) void*)g,
        (__attribute__((address_space(3))) void*)l, 16, 0, 0);
}

// ---------------------------------------------------------------------------
// Pre-split f32 -> (hi bf16, lo bf16) for obj, q, vw, qw.
// ---------------------------------------------------------------------------
__global__ __launch_bounds__(256)
void cvt_split(const float* __restrict__ obj, const float* __restrict__ q,
               const float* __restrict__ vw, const float* __restrict__ qw,
               short* __restrict__ objh, short* __restrict__ objl,
               short* __restrict__ qh, short* __restrict__ ql,
               short* __restrict__ vwh, short* __restrict__ vwl,
               short* __restrict__ qwh, short* __restrict__ qwl)
{
    const int bid = blockIdx.x;
    const float* src; short* hi; short* lo; int base4;
    if (bid < 192)      { src = obj; hi = objh; lo = objl; base4 = bid * 1024; }
    else if (bid < 576) { src = q;   hi = qh;   lo = ql;   base4 = (bid - 192) * 1024; }
    else if (bid < 768) { src = vw;  hi = vwh;  lo = vwl;  base4 = (bid - 576) * 1024; }
    else                { src = qw;  hi = qwh;  lo = qwl;  base4 = (bid - 768) * 1024; }
    #pragma unroll
    for (int it = 0; it < 4; ++it) {
        const size_t f4 = (size_t)base4 + it * 256 + threadIdx.x;
        const float4 v = *(const float4*)(src + f4 * 4);
        const float ff[4] = {v.x, v.y, v.z, v.w};
        s16x4 h4, l4;
        #pragma unroll
        for (int e = 0; e < 4; ++e) { h4[e] = bf_hi(ff[e]); l4[e] = bf_lo(ff[e]); }
        *(s16x4*)(hi + f4 * 4) = h4;
        *(s16x4*)(lo + f4 * 4) = l4;
    }
}

// ---------------------------------------------------------------------------
// Unified split-bf16 NT GEMM on pre-split operands (unchanged; verified).
// Blocks [0,256):  W[b][h][o] (transposed split-bf16) = obj[b*64+o,:] . vw[h,:]
// Blocks [256,768): u[m][h] f32 = relu(q[m,:] . qw[h,:] + qb[h]) * lw[h]
// ---------------------------------------------------------------------------
__global__ __launch_bounds__(256)
void gemm_split(const short* __restrict__ objh, const short* __restrict__ objl,
                const short* __restrict__ qh, const short* __restrict__ ql,
                const short* __restrict__ vwh, const short* __restrict__ vwl,
                const short* __restrict__ qwh, const short* __restrict__ qwl,
                const float* __restrict__ qb, const float* __restrict__ lwp,
                short* __restrict__ Wth, short* __restrict__ Wtl,
                float* __restrict__ ub)
{
    __shared__ __align__(16) short lds[4 * 4096];   // Xh | Xl | Bh | Bl (64x64 each)
    const int bid = blockIdx.x;
    const bool isA = bid < 256;
    const int lb_ = isA ? bid : bid - 256;
    const int r0 = (lb_ >> 4) * 64;
    const int h0 = (lb_ & 15) * 64;
    const short* Xh = isA ? objh : qh;
    const short* Xl = isA ? objl : ql;
    const short* Bh = isA ? vwh : qwh;
    const short* Bl = isA ? vwl : qwl;

    const int tid = threadIdx.x;
    const int w = tid >> 6, l = tid & 63;
    const int wm = (w >> 1) * 32, wn = (w & 1) * 32;
    const int g = l >> 4, c16 = l & 15;

    const int row0 = tid >> 3, u0 = (tid & 7) ^ (row0 & 7);
    const int unit1 = 256 + tid;
    const int row1 = unit1 >> 3, u1 = (unit1 & 7) ^ (row1 & 7);
    const short* pXh = Xh + (size_t)r0 * VD_;
    const short* pXl = Xl + (size_t)r0 * VD_;
    const short* pBh = Bh + (size_t)h0 * VD_;
    const short* pBl = Bl + (size_t)h0 * VD_;
    int go0 = row0 * VD_ + u0 * 8;
    int go1 = row1 * VD_ + u1 * 8;
    short* const d0 = &lds[w * 512];

    f32x4 acc[2][2] = {};

    for (int c = 0; c < VD_ / 64; ++c) {
        __syncthreads();
        gload16(pXh + go0, d0);
        gload16(pXh + go1, d0 + 2048);
        gload16(pXl + go0, d0 + 4096);
        gload16(pXl + go1, d0 + 4096 + 2048);
        gload16(pBh + go0, d0 + 8192);
        gload16(pBh + go1, d0 + 8192 + 2048);
        gload16(pBl + go0, d0 + 12288);
        gload16(pBl + go1, d0 + 12288 + 2048);
        go0 += 64; go1 += 64;
        __syncthreads();
        #pragma unroll
        for (int s = 0; s < 2; ++s) {
            s16x8 ah[2], al[2], bh2[2], bl2[2];
            #pragma unroll
            for (int i = 0; i < 2; ++i) {
                const int m = wm + i * 16 + c16;
                const int us = (((s * 4 + g) ^ (m & 7)) * 8);
                ah[i]  = *(const s16x8*)&lds[m * 64 + us];
                al[i]  = *(const s16x8*)&lds[4096 + m * 64 + us];
                const int n = wn + i * 16 + c16;
                const int vs = (((s * 4 + g) ^ (n & 7)) * 8);
                bh2[i] = *(const s16x8*)&lds[8192 + n * 64 + vs];
                bl2[i] = *(const s16x8*)&lds[12288 + n * 64 + vs];
            }
            #pragma unroll
            for (int i = 0; i < 2; ++i)
                #pragma unroll
                for (int j = 0; j < 2; ++j) {
                    acc[i][j] = MFMA(ah[i], bh2[j], acc[i][j]);
                    acc[i][j] = MFMA(ah[i], bl2[j], acc[i][j]);
                    acc[i][j] = MFMA(al[i], bh2[j], acc[i][j]);
                }
        }
    }

    #pragma unroll
    for (int i = 0; i < 2; ++i)
        #pragma unroll
        for (int j = 0; j < 2; ++j) {
            const int h = h0 + wn + j * 16 + c16;
            if (isA) {
                const int o = wm + i * 16 + g * 4;
                s16x4 hi4, lo4;
                #pragma unroll
                for (int r = 0; r < 4; ++r) {
                    hi4[r] = bf_hi(acc[i][j][r]);
                    lo4[r] = bf_lo(acc[i][j][r]);
                }
                const size_t dst = ((size_t)(lb_ >> 4) * H_ + h) * O_ + o;
                *(s16x4*)&Wth[dst] = hi4;
                *(s16x4*)&Wtl[dst] = lo4;
            } else {
                const float bv = qb[h], sv = lwp[h];
                #pragma unroll
                for (int r = 0; r < 4; ++r) {
                    const int m = r0 + wm + i * 16 + g * 4 + r;
                    ub[(size_t)m * H_ + h] = fmaxf(acc[i][j][r] + bv, 0.f) * sv;
                }
            }
        }
}

// ---------------------------------------------------------------------------
// Stage 1 v2: per (b, n-pair, h-half) block, partial logits over 512 h.
// W staged in double-buffered LDS chunks (64h x 64o hi+lo = 16 KB) via
// global_load_lds; A-frags in registers; no register prefetch (no spills).
// ---------------------------------------------------------------------------
__global__ __launch_bounds__(256, 3)
void logits_part(const float* __restrict__ att1, const short* __restrict__ Wth,
                 const short* __restrict__ Wtl, const float* __restrict__ ub,
                 const float* __restrict__ vb, float* __restrict__ lgws)
{
    __shared__ __align__(16) short Ah[64 * 64], Al[64 * 64];
    __shared__ __align__(16) short Wc[2][2][64 * 64];   // [buf][hi/lo][h*64+o]
    __shared__ float lgp[4][64];

    const int blk = blockIdx.x;          // ((b*64+pair)*2 + half)
    const int b = blk >> 7;
    const int pair = (blk >> 1) & 63;
    const int half = blk & 1;
    const int n0 = pair * 2;
    const int tid = threadIdx.x;
    const size_t base_row = (size_t)(b * N_ + n0) * A_;

    {   // stage att1 tile as swizzled split-bf16
        const int row = tid >> 2, qq = tid & 3;
        const float* src = att1 + (base_row + row) * O_ + qq * 16;
        #pragma unroll
        for (int uu = 0; uu < 2; ++uu) {
            const float4 f0 = *(const float4*)(src + uu * 8);
            const float4 f1 = *(const float4*)(src + uu * 8 + 4);
            const int us = ((qq * 2 + uu) ^ (row & 7)) * 8;
            s16x8 hi, lo; cvt8(f0, f1, hi, lo);
            *(s16x8*)&Ah[row * 64 + us] = hi;
            *(s16x8*)&Al[row * 64 + us] = lo;
        }
    }

    const int w = tid >> 6, l = tid & 63;
    const int g = l >> 4, c16 = l & 15;

    // W chunk staging: linear LDS dest (unit = tid + k*256), pre-swizzled src
    const int row0 = tid >> 3;                        // 0..31
    const int usrc = (tid & 7) ^ (row0 & 7);
    const int off0 = row0 * 64 + usrc * 8;            // shorts; row0+32 same xor
    const int off1 = off0 + 2048;
    const size_t wcb = ((size_t)b * H_ + half * 512) * O_;
    const short* pWh = Wth + wcb;
    const short* pWl = Wtl + wcb;

#define STAGEW(BUF, CI) do { \
        const short* ph_ = pWh + (size_t)(CI) * 4096; \
        const short* pl_ = pWl + (size_t)(CI) * 4096; \
        gload16(ph_ + off0, &Wc[BUF][0][w * 512]); \
        gload16(ph_ + off1, &Wc[BUF][0][w * 512 + 2048]); \
        gload16(pl_ + off0, &Wc[BUF][1][w * 512]); \
        gload16(pl_ + off1, &Wc[BUF][1][w * 512 + 2048]); \
    } while (0)

    STAGEW(0, 0);
    __syncthreads();     // drains vmcnt(0): chunk 0 + A tile visible

    // A fragments, held for the whole sweep (16 frags = 64 VGPRs)
    s16x8 ahf[4][2], alf[4][2];
    #pragma unroll
    for (int i = 0; i < 4; ++i)
        #pragma unroll
        for (int s = 0; s < 2; ++s) {
            const int m = i * 16 + c16;
            const int us = ((s * 4 + g) ^ (m & 7)) * 8;
            ahf[i][s] = *(const s16x8*)&Ah[m * 64 + us];
            alf[i][s] = *(const s16x8*)&Al[m * 64 + us];
        }

    const float* vbp = vb + half * 512 + w * 16 + c16;
    const float* u0p = ub + (size_t)(b * N_ + n0) * H_ + half * 512 + w * 16 + c16;
    const float* u1p = u0p + H_;

    const int sr = c16 & 7;
    const int rbase = (w * 16 + c16) * 64;
    const int ubo0 = (g ^ sr) * 8;
    const int ubo1 = ((g + 4) ^ sr) * 8;

    f32x4 part[4] = {};

    #pragma unroll 2
    for (int c = 0; c < 8; ++c) {
        const int cur = c & 1;
        if (c < 7) STAGEW(cur ^ 1, c + 1);
        const float vbv = vbp[c * 64];
        const float uu0 = u0p[c * 64];
        const float uu1 = u1p[c * 64];
        const s16x8 bh0 = *(const s16x8*)&Wc[cur][0][rbase + ubo0];
        const s16x8 bh1 = *(const s16x8*)&Wc[cur][0][rbase + ubo1];
        const s16x8 bl0 = *(const s16x8*)&Wc[cur][1][rbase + ubo0];
        const s16x8 bl1 = *(const s16x8*)&Wc[cur][1][rbase + ubo1];
        #pragma unroll
        for (int i = 0; i < 4; ++i) {
            f32x4 acc = {};
            acc = MFMA(ahf[i][0], bh0, acc);
            acc = MFMA(alf[i][0], bh0, acc);
            acc = MFMA(ahf[i][0], bl0, acc);
            acc = MFMA(ahf[i][1], bh1, acc);
            acc = MFMA(alf[i][1], bh1, acc);
            acc = MFMA(ahf[i][1], bl1, acc);
            const float uu = (i < 2) ? uu0 : uu1;
            #pragma unroll
            for (int r = 0; r < 4; ++r)
                part[i][r] += fmaxf(acc[r] + vbv, 0.f) * uu;
        }
        __syncthreads();   // drains stage vmcnt; consume->restage ordering
    }
#undef STAGEW

    #pragma unroll
    for (int i = 0; i < 4; ++i)
        #pragma unroll
        for (int r = 0; r < 4; ++r) {
            float v = part[i][r];
            v += __shfl_xor(v, 1, 64);
            v += __shfl_xor(v, 2, 64);
            v += __shfl_xor(v, 4, 64);
            v += __shfl_xor(v, 8, 64);
            if (c16 == 0) lgp[w][i * 16 + g * 4 + r] = v;
        }
    __syncthreads();

    if (tid < 64) {
        const float s = lgp[0][tid] + lgp[1][tid] + lgp[2][tid] + lgp[3][tid];
        lgws[(size_t)(blk >> 1) * 128 + half * 64 + tid] = s;
    }
}

// ---------------------------------------------------------------------------
// Stage 2: combine halves, mask, softmax, att2 @ att1. One block per n-pair.
// ---------------------------------------------------------------------------
__global__ __launch_bounds__(128)
void finish(const float* __restrict__ att1, const float* __restrict__ lgws,
            const int* __restrict__ tags, const int* __restrict__ tptr,
            const float* __restrict__ lbptr, float* __restrict__ out)
{
    __shared__ float sml[64];
    const int pg = blockIdx.x;           // 0..1023
    const int b = pg >> 6, n0 = (pg & 63) * 2;
    const int tid = threadIdx.x;
    const size_t base_row = (size_t)(b * N_ + n0) * A_;

    if (tid < 64) {
        const float tf = (float)(*tptr);
        const float lv = (lgws[(size_t)pg * 128 + tid] +
                          lgws[(size_t)pg * 128 + 64 + tid] + *lbptr) / tf;
        const int tg = tags[base_row + tid];
        sml[tid] = (tg > 0) ? lv : -1e30f;
    }
    __syncthreads();

    const int nn = tid >> 6, o = tid & 63;
    const float* lr = &sml[nn * 32];
    float m = -3.0e38f;
    #pragma unroll
    for (int a = 0; a < 32; ++a) m = fmaxf(m, lr[a]);
    float s = 0.f, accum = 0.f;
    #pragma unroll
    for (int a = 0; a < 32; ++a) {
        const float e = __expf(lr[a] - m);
        s += e;
        accum += e * att1[(base_row + nn * 32 + a) * O_ + o];
    }
    out[(size_t)(b * N_ + n0 + nn) * O_ + o] = accum / s;
}

extern "C" void kernel_launch(void* const* d_in, const int* in_sizes, int n_in,
                              void* d_out, int out_size, void* d_ws, size_t ws_size,
                              hipStream_t stream)
{
    const float* q    = (const float*)d_in[0];
    const float* att1 = (const float*)d_in[1];
    const float* obj  = (const float*)d_in[2];
    const int*   tags = (const int*)d_in[3];
    const int*   tptr = (const int*)d_in[4];
    const float* vw   = (const float*)d_in[5];
    const float* vb   = (const float*)d_in[6];
    const float* qw   = (const float*)d_in[7];
    const float* qb   = (const float*)d_in[8];
    const float* lw   = (const float*)d_in[9];
    const float* lb   = (const float*)d_in[10];
    float* out = (float*)d_out;

    float* ub   = (float*)d_ws;                         // [2048][1024] f32   8 MB
    float* lgws = ub + (size_t)B_ * N_ * H_;            // [1024][128] f32    512 KB
    short* Wth  = (short*)(lgws + 1024 * 128);          // [16][1024][64]     2 MB
    short* Wtl  = Wth + (size_t)B_ * H_ * O_;           //                    2 MB
    short* objh = Wtl + (size_t)B_ * H_ * O_;           // [1024][768]        1.5 MB
    short* objl = objh + (size_t)1024 * VD_;
    short* qh   = objl + (size_t)1024 * VD_;            // [2048][768]        3 MB
    short* ql   = qh + (size_t)2048 * VD_;
    short* vwh  = ql + (size_t)2048 * VD_;              // [1024][768]
    short* vwl  = vwh + (size_t)H_ * VD_;
    short* qwh  = vwl + (size_t)H_ * VD_;
    short* qwl  = qwh + (size_t)H_ * VD_;

    cvt_split<<<960, 256, 0, stream>>>(obj, q, vw, qw, objh, objl, qh, ql,
                                       vwh, vwl, qwh, qwl);
    gemm_split<<<768, 256, 0, stream>>>(objh, objl, qh, ql, vwh, vwl, qwh, qwl,
                                        qb, lw, Wth, Wtl, ub);
    logits_part<<<B_ * 64 * 2, 256, 0, stream>>>(att1, Wth, Wtl, ub, vb, lgws);
    finish<<<B_ * 64, 128, 0, stream>>>(att1, lgws, tags, tptr, lb, out);
}

// Round 5
// 70.981 us; speedup vs baseline: 1.8935x; 1.0362x over previous
//
#include <hip/hip_runtime.h>

#define B_ 16
#define N_ 128
#define A_ 32
#define O_ 64
#define VD_ 768
#define H_ 1024

typedef short s16x8 __attribute__((ext_vector_type(8)));
typedef short s16x4 __attribute__((ext_vector_type(4)));
typedef float f32x4 __attribute__((ext_vector_type(4)));

#define MFMA(a, b, c) __builtin_amdgcn_mfma_f32_16x16x32_bf16(a, b, c, 0, 0, 0)

__device__ __forceinline__ short bf_hi(float x) {
    return (short)(__float_as_uint(x) >> 16);
}
__device__ __forceinline__ short bf_lo(float x) {
    float r = x - __uint_as_float(__float_as_uint(x) & 0xffff0000u);
    return (short)(__float_as_uint(r) >> 16);
}
__device__ __forceinline__ void cvt8(const float4& f0, const float4& f1,
                                     s16x8& hi, s16x8& lo) {
    const float ff[8] = {f0.x, f0.y, f0.z, f0.w, f1.x, f1.y, f1.z, f1.w};
    #pragma unroll
    for (int e = 0; e < 8; ++e) { hi[e] = bf_hi(ff[e]); lo[e] = bf_lo(ff[e]); }
}

__device__ __forceinline__ void gload16(const void* g, void* l) {
    __builtin_amdgcn_global_load_lds(
        (const __attribute__((address_space(1))) void*)g,
        (__attribute__((address_space(3))) void*)l, 16, 0, 0);
}

// ---------------------------------------------------------------------------
// Pre-split f32 -> (hi bf16, lo bf16) for obj, q, vw, qw.
// ---------------------------------------------------------------------------
__global__ __launch_bounds__(256)
void cvt_split(const float* __restrict__ obj, const float* __restrict__ q,
               const float* __restrict__ vw, const float* __restrict__ qw,
               short* __restrict__ objh, short* __restrict__ objl,
               short* __restrict__ qh, short* __restrict__ ql,
               short* __restrict__ vwh, short* __restrict__ vwl,
               short* __restrict__ qwh, short* __restrict__ qwl)
{
    const int bid = blockIdx.x;
    const float* src; short* hi; short* lo; int base4;
    if (bid < 192)      { src = obj; hi = objh; lo = objl; base4 = bid * 1024; }
    else if (bid < 576) { src = q;   hi = qh;   lo = ql;   base4 = (bid - 192) * 1024; }
    else if (bid < 768) { src = vw;  hi = vwh;  lo = vwl;  base4 = (bid - 576) * 1024; }
    else                { src = qw;  hi = qwh;  lo = qwl;  base4 = (bid - 768) * 1024; }
    #pragma unroll
    for (int it = 0; it < 4; ++it) {
        const size_t f4 = (size_t)base4 + it * 256 + threadIdx.x;
        const float4 v = *(const float4*)(src + f4 * 4);
        const float ff[4] = {v.x, v.y, v.z, v.w};
        s16x4 h4, l4;
        #pragma unroll
        for (int e = 0; e < 4; ++e) { h4[e] = bf_hi(ff[e]); l4[e] = bf_lo(ff[e]); }
        *(s16x4*)(hi + f4 * 4) = h4;
        *(s16x4*)(lo + f4 * 4) = l4;
    }
}

// ---------------------------------------------------------------------------
// Unified split-bf16 NT GEMM on pre-split operands (unchanged; verified).
// Blocks [0,256):  W[b][h][o] (transposed split-bf16) = obj[b*64+o,:] . vw[h,:]
// Blocks [256,768): u[m][h] f32 = relu(q[m,:] . qw[h,:] + qb[h]) * lw[h]
// ---------------------------------------------------------------------------
__global__ __launch_bounds__(256)
void gemm_split(const short* __restrict__ objh, const short* __restrict__ objl,
                const short* __restrict__ qh, const short* __restrict__ ql,
                const short* __restrict__ vwh, const short* __restrict__ vwl,
                const short* __restrict__ qwh, const short* __restrict__ qwl,
                const float* __restrict__ qb, const float* __restrict__ lwp,
                short* __restrict__ Wth, short* __restrict__ Wtl,
                float* __restrict__ ub)
{
    __shared__ __align__(16) short lds[4 * 4096];   // Xh | Xl | Bh | Bl (64x64 each)
    const int bid = blockIdx.x;
    const bool isA = bid < 256;
    const int lb_ = isA ? bid : bid - 256;
    const int r0 = (lb_ >> 4) * 64;
    const int h0 = (lb_ & 15) * 64;
    const short* Xh = isA ? objh : qh;
    const short* Xl = isA ? objl : ql;
    const short* Bh = isA ? vwh : qwh;
    const short* Bl = isA ? vwl : qwl;

    const int tid = threadIdx.x;
    const int w = tid >> 6, l = tid & 63;
    const int wm = (w >> 1) * 32, wn = (w & 1) * 32;
    const int g = l >> 4, c16 = l & 15;

    const int row0 = tid >> 3, u0 = (tid & 7) ^ (row0 & 7);
    const int unit1 = 256 + tid;
    const int row1 = unit1 >> 3, u1 = (unit1 & 7) ^ (row1 & 7);
    const short* pXh = Xh + (size_t)r0 * VD_;
    const short* pXl = Xl + (size_t)r0 * VD_;
    const short* pBh = Bh + (size_t)h0 * VD_;
    const short* pBl = Bl + (size_t)h0 * VD_;
    int go0 = row0 * VD_ + u0 * 8;
    int go1 = row1 * VD_ + u1 * 8;
    short* const d0 = &lds[w * 512];

    f32x4 acc[2][2] = {};

    for (int c = 0; c < VD_ / 64; ++c) {
        __syncthreads();
        gload16(pXh + go0, d0);
        gload16(pXh + go1, d0 + 2048);
        gload16(pXl + go0, d0 + 4096);
        gload16(pXl + go1, d0 + 4096 + 2048);
        gload16(pBh + go0, d0 + 8192);
        gload16(pBh + go1, d0 + 8192 + 2048);
        gload16(pBl + go0, d0 + 12288);
        gload16(pBl + go1, d0 + 12288 + 2048);
        go0 += 64; go1 += 64;
        __syncthreads();
        #pragma unroll
        for (int s = 0; s < 2; ++s) {
            s16x8 ah[2], al[2], bh2[2], bl2[2];
            #pragma unroll
            for (int i = 0; i < 2; ++i) {
                const int m = wm + i * 16 + c16;
                const int us = (((s * 4 + g) ^ (m & 7)) * 8);
                ah[i]  = *(const s16x8*)&lds[m * 64 + us];
                al[i]  = *(const s16x8*)&lds[4096 + m * 64 + us];
                const int n = wn + i * 16 + c16;
                const int vs = (((s * 4 + g) ^ (n & 7)) * 8);
                bh2[i] = *(const s16x8*)&lds[8192 + n * 64 + vs];
                bl2[i] = *(const s16x8*)&lds[12288 + n * 64 + vs];
            }
            #pragma unroll
            for (int i = 0; i < 2; ++i)
                #pragma unroll
                for (int j = 0; j < 2; ++j) {
                    acc[i][j] = MFMA(ah[i], bh2[j], acc[i][j]);
                    acc[i][j] = MFMA(ah[i], bl2[j], acc[i][j]);
                    acc[i][j] = MFMA(al[i], bh2[j], acc[i][j]);
                }
        }
    }

    #pragma unroll
    for (int i = 0; i < 2; ++i)
        #pragma unroll
        for (int j = 0; j < 2; ++j) {
            const int h = h0 + wn + j * 16 + c16;
            if (isA) {
                const int o = wm + i * 16 + g * 4;
                s16x4 hi4, lo4;
                #pragma unroll
                for (int r = 0; r < 4; ++r) {
                    hi4[r] = bf_hi(acc[i][j][r]);
                    lo4[r] = bf_lo(acc[i][j][r]);
                }
                const size_t dst = ((size_t)(lb_ >> 4) * H_ + h) * O_ + o;
                *(s16x4*)&Wth[dst] = hi4;
                *(s16x4*)&Wtl[dst] = lo4;
            } else {
                const float bv = qb[h], sv = lwp[h];
                #pragma unroll
                for (int r = 0; r < 4; ++r) {
                    const int m = r0 + wm + i * 16 + g * 4 + r;
                    ub[(size_t)m * H_ + h] = fmaxf(acc[i][j][r] + bv, 0.f) * sv;
                }
            }
        }
}

// ---------------------------------------------------------------------------
// Fused: per (b, n-pair) block, full 1024-h sweep + softmax + att2 @ att1.
// W staged in double-buffered LDS chunks (64h x 64o hi+lo = 16 KB) via
// global_load_lds; A-frags in registers; epilogue reconstructs f32 att1
// from the hi/lo LDS tiles (no separate f32 copy, no second kernel).
// ---------------------------------------------------------------------------
__global__ __launch_bounds__(256, 3)
void fused_logits(const float* __restrict__ att1, const short* __restrict__ Wth,
                  const short* __restrict__ Wtl, const float* __restrict__ ub,
                  const float* __restrict__ vb, const int* __restrict__ tags,
                  const int* __restrict__ tptr, const float* __restrict__ lbptr,
                  float* __restrict__ out)
{
    __shared__ __align__(16) short Ah[64 * 64], Al[64 * 64];
    __shared__ __align__(16) short Wc[2][2][64 * 64];   // [buf][hi/lo][h*64+o]
    __shared__ float lgp[4][64];
    __shared__ float sml[64];

    const int blk = blockIdx.x;          // b*64 + pair
    const int b = blk >> 6;
    const int n0 = (blk & 63) * 2;
    const int tid = threadIdx.x;
    const size_t base_row = (size_t)(b * N_ + n0) * A_;

    {   // stage att1 tile as swizzled split-bf16 (once per pair)
        const int row = tid >> 2, qq = tid & 3;
        const float* src = att1 + (base_row + row) * O_ + qq * 16;
        #pragma unroll
        for (int uu = 0; uu < 2; ++uu) {
            const float4 f0 = *(const float4*)(src + uu * 8);
            const float4 f1 = *(const float4*)(src + uu * 8 + 4);
            const int us = ((qq * 2 + uu) ^ (row & 7)) * 8;
            s16x8 hi, lo; cvt8(f0, f1, hi, lo);
            *(s16x8*)&Ah[row * 64 + us] = hi;
            *(s16x8*)&Al[row * 64 + us] = lo;
        }
    }

    const int w = tid >> 6, l = tid & 63;
    const int g = l >> 4, c16 = l & 15;

    // W chunk staging: linear LDS dest (unit = tid + k*256), pre-swizzled src
    const int row0 = tid >> 3;                        // 0..31
    const int usrc = (tid & 7) ^ (row0 & 7);
    const int off0 = row0 * 64 + usrc * 8;            // shorts
    const int off1 = off0 + 2048;
    const short* pWh = Wth + (size_t)b * H_ * O_;
    const short* pWl = Wtl + (size_t)b * H_ * O_;

#define STAGEW(BUF, CI) do { \
        const short* ph_ = pWh + (size_t)(CI) * 4096; \
        const short* pl_ = pWl + (size_t)(CI) * 4096; \
        gload16(ph_ + off0, &Wc[BUF][0][w * 512]); \
        gload16(ph_ + off1, &Wc[BUF][0][w * 512 + 2048]); \
        gload16(pl_ + off0, &Wc[BUF][1][w * 512]); \
        gload16(pl_ + off1, &Wc[BUF][1][w * 512 + 2048]); \
    } while (0)

    STAGEW(0, 0);
    __syncthreads();     // drains vmcnt(0): chunk 0 + A tile visible

    // A fragments, held for the whole sweep (16 frags = 64 VGPRs)
    s16x8 ahf[4][2], alf[4][2];
    #pragma unroll
    for (int i = 0; i < 4; ++i)
        #pragma unroll
        for (int s = 0; s < 2; ++s) {
            const int m = i * 16 + c16;
            const int us = ((s * 4 + g) ^ (m & 7)) * 8;
            ahf[i][s] = *(const s16x8*)&Ah[m * 64 + us];
            alf[i][s] = *(const s16x8*)&Al[m * 64 + us];
        }

    const float* vbp = vb + w * 16 + c16;
    const float* u0p = ub + (size_t)(b * N_ + n0) * H_ + w * 16 + c16;
    const float* u1p = u0p + H_;

    const int sr = c16 & 7;
    const int rbase = (w * 16 + c16) * 64;
    const int ubo0 = (g ^ sr) * 8;
    const int ubo1 = ((g + 4) ^ sr) * 8;

    f32x4 part[4] = {};

    #pragma unroll 2
    for (int c = 0; c < 16; ++c) {
        const int cur = c & 1;
        if (c < 15) STAGEW(cur ^ 1, c + 1);
        const float vbv = vbp[c * 64];
        const float uu0 = u0p[c * 64];
        const float uu1 = u1p[c * 64];
        const s16x8 bh0 = *(const s16x8*)&Wc[cur][0][rbase + ubo0];
        const s16x8 bh1 = *(const s16x8*)&Wc[cur][0][rbase + ubo1];
        const s16x8 bl0 = *(const s16x8*)&Wc[cur][1][rbase + ubo0];
        const s16x8 bl1 = *(const s16x8*)&Wc[cur][1][rbase + ubo1];
        #pragma unroll
        for (int i = 0; i < 4; ++i) {
            f32x4 acc = {};
            acc = MFMA(ahf[i][0], bh0, acc);
            acc = MFMA(alf[i][0], bh0, acc);
            acc = MFMA(ahf[i][0], bl0, acc);
            acc = MFMA(ahf[i][1], bh1, acc);
            acc = MFMA(alf[i][1], bh1, acc);
            acc = MFMA(ahf[i][1], bl1, acc);
            const float uu = (i < 2) ? uu0 : uu1;
            #pragma unroll
            for (int r = 0; r < 4; ++r)
                part[i][r] += fmaxf(acc[r] + vbv, 0.f) * uu;
        }
        __syncthreads();   // drains stage vmcnt; consume->restage ordering
    }
#undef STAGEW

    #pragma unroll
    for (int i = 0; i < 4; ++i)
        #pragma unroll
        for (int r = 0; r < 4; ++r) {
            float v = part[i][r];
            v += __shfl_xor(v, 1, 64);
            v += __shfl_xor(v, 2, 64);
            v += __shfl_xor(v, 4, 64);
            v += __shfl_xor(v, 8, 64);
            if (c16 == 0) lgp[w][i * 16 + g * 4 + r] = v;
        }
    __syncthreads();

    if (tid < 64) {
        const float tf = (float)(*tptr);
        const float lsum = lgp[0][tid] + lgp[1][tid] + lgp[2][tid] + lgp[3][tid];
        const float lv = (lsum + *lbptr) / tf;
        const int tg = tags[base_row + tid];
        sml[tid] = (tg > 0) ? lv : -1e30f;
    }
    __syncthreads();

    if (tid < 128) {
        const int nn = tid >> 6, o = tid & 63;
        const float* lr = &sml[nn * 32];
        const int uo = (o >> 3);          // 8-elem unit of column o
        const int oe = (o & 7);
        float m = -3.0e38f;
        #pragma unroll
        for (int a = 0; a < 32; ++a) m = fmaxf(m, lr[a]);
        float s = 0.f, accum = 0.f;
        #pragma unroll
        for (int a = 0; a < 32; ++a) {
            const int row = nn * 32 + a;
            const int idx = row * 64 + ((uo ^ (row & 7)) * 8 + oe);
            const float a1 =
                __uint_as_float(((unsigned)(unsigned short)Ah[idx]) << 16) +
                __uint_as_float(((unsigned)(unsigned short)Al[idx]) << 16);
            const float e = __expf(lr[a] - m);
            s += e;
            accum += e * a1;
        }
        out[(size_t)(b * N_ + n0 + nn) * O_ + o] = accum / s;
    }
}

extern "C" void kernel_launch(void* const* d_in, const int* in_sizes, int n_in,
                              void* d_out, int out_size, void* d_ws, size_t ws_size,
                              hipStream_t stream)
{
    const float* q    = (const float*)d_in[0];
    const float* att1 = (const float*)d_in[1];
    const float* obj  = (const float*)d_in[2];
    const int*   tags = (const int*)d_in[3];
    const int*   tptr = (const int*)d_in[4];
    const float* vw   = (const float*)d_in[5];
    const float* vb   = (const float*)d_in[6];
    const float* qw   = (const float*)d_in[7];
    const float* qb   = (const float*)d_in[8];
    const float* lw   = (const float*)d_in[9];
    const float* lb   = (const float*)d_in[10];
    float* out = (float*)d_out;

    float* ub   = (float*)d_ws;                         // [2048][1024] f32   8 MB
    short* Wth  = (short*)(ub + (size_t)B_ * N_ * H_);  // [16][1024][64]     2 MB
    short* Wtl  = Wth + (size_t)B_ * H_ * O_;           //                    2 MB
    short* objh = Wtl + (size_t)B_ * H_ * O_;           // [1024][768]        1.5 MB
    short* objl = objh + (size_t)1024 * VD_;
    short* qh   = objl + (size_t)1024 * VD_;            // [2048][768]        3 MB
    short* ql   = qh + (size_t)2048 * VD_;
    short* vwh  = ql + (size_t)2048 * VD_;              // [1024][768]
    short* vwl  = vwh + (size_t)H_ * VD_;
    short* qwh  = vwl + (size_t)H_ * VD_;
    short* qwl  = qwh + (size_t)H_ * VD_;

    cvt_split<<<960, 256, 0, stream>>>(obj, q, vw, qw, objh, objl, qh, ql,
                                       vwh, vwl, qwh, qwl);
    gemm_split<<<768, 256, 0, stream>>>(objh, objl, qh, ql, vwh, vwl, qwh, qwl,
                                        qb, lw, Wth, Wtl, ub);
    fused_logits<<<B_ * 64, 256, 0, stream>>>(att1, Wth, Wtl, ub, vb, tags,
                                              tptr, lb, out);
}

// Round 6
// 65.986 us; speedup vs baseline: 2.0368x; 1.0757x over previous
//
#include <hip/hip_runtime.h>

#define B_ 16
#define N_ 128
#define A_ 32
#define O_ 64
#define VD_ 768
#define H_ 1024

typedef short s16x8 __attribute__((ext_vector_type(8)));
typedef short s16x4 __attribute__((ext_vector_type(4)));
typedef float f32x4 __attribute__((ext_vector_type(4)));

#define MFMA(a, b, c) __builtin_amdgcn_mfma_f32_16x16x32_bf16(a, b, c, 0, 0, 0)

__device__ __forceinline__ short bf_hi(float x) {
    return (short)(__float_as_uint(x) >> 16);
}
__device__ __forceinline__ short bf_lo(float x) {
    float r = x - __uint_as_float(__float_as_uint(x) & 0xffff0000u);
    return (short)(__float_as_uint(r) >> 16);
}
__device__ __forceinline__ void cvt8(const float4& f0, const float4& f1,
                                     s16x8& hi, s16x8& lo) {
    const float ff[8] = {f0.x, f0.y, f0.z, f0.w, f1.x, f1.y, f1.z, f1.w};
    #pragma unroll
    for (int e = 0; e < 8; ++e) { hi[e] = bf_hi(ff[e]); lo[e] = bf_lo(ff[e]); }
}

__device__ __forceinline__ void gload16(const void* g, void* l) {
    __builtin_amdgcn_global_load_lds(
        (const __attribute__((address_space(1))) void*)g,
        (__attribute__((address_space(3))) void*)l, 16, 0, 0);
}

// ---------------------------------------------------------------------------
// Pre-split f32 -> (hi bf16, lo bf16) for obj, q, vw, qw.
// ---------------------------------------------------------------------------
__global__ __launch_bounds__(256)
void cvt_split(const float* __restrict__ obj, const float* __restrict__ q,
               const float* __restrict__ vw, const float* __restrict__ qw,
               short* __restrict__ objh, short* __restrict__ objl,
               short* __restrict__ qh, short* __restrict__ ql,
               short* __restrict__ vwh, short* __restrict__ vwl,
               short* __restrict__ qwh, short* __restrict__ qwl)
{
    const int bid = blockIdx.x;
    const float* src; short* hi; short* lo; int base4;
    if (bid < 192)      { src = obj; hi = objh; lo = objl; base4 = bid * 1024; }
    else if (bid < 576) { src = q;   hi = qh;   lo = ql;   base4 = (bid - 192) * 1024; }
    else if (bid < 768) { src = vw;  hi = vwh;  lo = vwl;  base4 = (bid - 576) * 1024; }
    else                { src = qw;  hi = qwh;  lo = qwl;  base4 = (bid - 768) * 1024; }
    #pragma unroll
    for (int it = 0; it < 4; ++it) {
        const size_t f4 = (size_t)base4 + it * 256 + threadIdx.x;
        const float4 v = *(const float4*)(src + f4 * 4);
        const float ff[4] = {v.x, v.y, v.z, v.w};
        s16x4 h4, l4;
        #pragma unroll
        for (int e = 0; e < 4; ++e) { h4[e] = bf_hi(ff[e]); l4[e] = bf_lo(ff[e]); }
        *(s16x4*)(hi + f4 * 4) = h4;
        *(s16x4*)(lo + f4 * 4) = l4;
    }
}

// ---------------------------------------------------------------------------
// Unified split-bf16 NT GEMM on pre-split operands (structure unchanged).
// Blocks [0,256):  W[b][h][o] (transposed bf16-hi only) = obj[b*64+o,:].vw[h,:]
// Blocks [256,768): u[m][h] f32 = relu(q[m,:] . qw[h,:] + qb[h]) * lw[h]
// ---------------------------------------------------------------------------
__global__ __launch_bounds__(256)
void gemm_split(const short* __restrict__ objh, const short* __restrict__ objl,
                const short* __restrict__ qh, const short* __restrict__ ql,
                const short* __restrict__ vwh, const short* __restrict__ vwl,
                const short* __restrict__ qwh, const short* __restrict__ qwl,
                const float* __restrict__ qb, const float* __restrict__ lwp,
                short* __restrict__ Wth, float* __restrict__ ub)
{
    __shared__ __align__(16) short lds[4 * 4096];   // Xh | Xl | Bh | Bl (64x64 each)
    const int bid = blockIdx.x;
    const bool isA = bid < 256;
    const int lb_ = isA ? bid : bid - 256;
    const int r0 = (lb_ >> 4) * 64;
    const int h0 = (lb_ & 15) * 64;
    const short* Xh = isA ? objh : qh;
    const short* Xl = isA ? objl : ql;
    const short* Bh = isA ? vwh : qwh;
    const short* Bl = isA ? vwl : qwl;

    const int tid = threadIdx.x;
    const int w = tid >> 6, l = tid & 63;
    const int wm = (w >> 1) * 32, wn = (w & 1) * 32;
    const int g = l >> 4, c16 = l & 15;

    const int row0 = tid >> 3, u0 = (tid & 7) ^ (row0 & 7);
    const int unit1 = 256 + tid;
    const int row1 = unit1 >> 3, u1 = (unit1 & 7) ^ (row1 & 7);
    const short* pXh = Xh + (size_t)r0 * VD_;
    const short* pXl = Xl + (size_t)r0 * VD_;
    const short* pBh = Bh + (size_t)h0 * VD_;
    const short* pBl = Bl + (size_t)h0 * VD_;
    int go0 = row0 * VD_ + u0 * 8;
    int go1 = row1 * VD_ + u1 * 8;
    short* const d0 = &lds[w * 512];

    f32x4 acc[2][2] = {};

    for (int c = 0; c < VD_ / 64; ++c) {
        __syncthreads();
        gload16(pXh + go0, d0);
        gload16(pXh + go1, d0 + 2048);
        gload16(pXl + go0, d0 + 4096);
        gload16(pXl + go1, d0 + 4096 + 2048);
        gload16(pBh + go0, d0 + 8192);
        gload16(pBh + go1, d0 + 8192 + 2048);
        gload16(pBl + go0, d0 + 12288);
        gload16(pBl + go1, d0 + 12288 + 2048);
        go0 += 64; go1 += 64;
        __syncthreads();
        #pragma unroll
        for (int s = 0; s < 2; ++s) {
            s16x8 ah[2], al[2], bh2[2], bl2[2];
            #pragma unroll
            for (int i = 0; i < 2; ++i) {
                const int m = wm + i * 16 + c16;
                const int us = (((s * 4 + g) ^ (m & 7)) * 8);
                ah[i]  = *(const s16x8*)&lds[m * 64 + us];
                al[i]  = *(const s16x8*)&lds[4096 + m * 64 + us];
                const int n = wn + i * 16 + c16;
                const int vs = (((s * 4 + g) ^ (n & 7)) * 8);
                bh2[i] = *(const s16x8*)&lds[8192 + n * 64 + vs];
                bl2[i] = *(const s16x8*)&lds[12288 + n * 64 + vs];
            }
            #pragma unroll
            for (int i = 0; i < 2; ++i)
                #pragma unroll
                for (int j = 0; j < 2; ++j) {
                    acc[i][j] = MFMA(ah[i], bh2[j], acc[i][j]);
                    acc[i][j] = MFMA(ah[i], bl2[j], acc[i][j]);
                    acc[i][j] = MFMA(al[i], bh2[j], acc[i][j]);
                }
        }
    }

    #pragma unroll
    for (int i = 0; i < 2; ++i)
        #pragma unroll
        for (int j = 0; j < 2; ++j) {
            const int h = h0 + wn + j * 16 + c16;
            if (isA) {
                const int o = wm + i * 16 + g * 4;
                s16x4 hi4;
                #pragma unroll
                for (int r = 0; r < 4; ++r) hi4[r] = bf_hi(acc[i][j][r]);
                const size_t dst = ((size_t)(lb_ >> 4) * H_ + h) * O_ + o;
                *(s16x4*)&Wth[dst] = hi4;
            } else {
                const float bv = qb[h], sv = lwp[h];
                #pragma unroll
                for (int r = 0; r < 4; ++r) {
                    const int m = r0 + wm + i * 16 + g * 4 + r;
                    ub[(size_t)m * H_ + h] = fmaxf(acc[i][j][r] + bv, 0.f) * sv;
                }
            }
        }
}

// ---------------------------------------------------------------------------
// Fused: per (b, n-pair) block, full 1024-h sweep + softmax + att2 @ att1.
// W staged hi-only in double-buffered LDS chunks (64h x 64o = 8 KB) via
// global_load_lds; A kept split (hi+lo) in registers; epilogue reconstructs
// f32 att1 from the hi/lo LDS tiles. LDS 33.3 KB -> 4 blocks/CU.
// ---------------------------------------------------------------------------
__global__ __launch_bounds__(256, 4)
void fused_logits(const float* __restrict__ att1, const short* __restrict__ Wth,
                  const float* __restrict__ ub, const float* __restrict__ vb,
                  const int* __restrict__ tags, const int* __restrict__ tptr,
                  const float* __restrict__ lbptr, float* __restrict__ out)
{
    __shared__ __align__(16) short Ah[64 * 64], Al[64 * 64];
    __shared__ __align__(16) short Wc[2][64 * 64];   // [buf][h*64+o], hi only
    __shared__ float lgp[4][64];
    __shared__ float sml[64];

    const int blk = blockIdx.x;          // b*64 + pair
    const int b = blk >> 6;
    const int n0 = (blk & 63) * 2;
    const int tid = threadIdx.x;
    const size_t base_row = (size_t)(b * N_ + n0) * A_;

    {   // stage att1 tile as swizzled split-bf16 (once per pair)
        const int row = tid >> 2, qq = tid & 3;
        const float* src = att1 + (base_row + row) * O_ + qq * 16;
        #pragma unroll
        for (int uu = 0; uu < 2; ++uu) {
            const float4 f0 = *(const float4*)(src + uu * 8);
            const float4 f1 = *(const float4*)(src + uu * 8 + 4);
            const int us = ((qq * 2 + uu) ^ (row & 7)) * 8;
            s16x8 hi, lo; cvt8(f0, f1, hi, lo);
            *(s16x8*)&Ah[row * 64 + us] = hi;
            *(s16x8*)&Al[row * 64 + us] = lo;
        }
    }

    const int w = tid >> 6, l = tid & 63;
    const int g = l >> 4, c16 = l & 15;

    // W chunk staging: linear LDS dest (unit = tid + k*256), pre-swizzled src
    const int row0 = tid >> 3;                        // 0..31
    const int usrc = (tid & 7) ^ (row0 & 7);
    const int off0 = row0 * 64 + usrc * 8;            // shorts
    const int off1 = off0 + 2048;
    const short* pWh = Wth + (size_t)b * H_ * O_;

#define STAGEW(BUF, CI) do { \
        const short* ph_ = pWh + (size_t)(CI) * 4096; \
        gload16(ph_ + off0, &Wc[BUF][w * 512]); \
        gload16(ph_ + off1, &Wc[BUF][w * 512 + 2048]); \
    } while (0)

    STAGEW(0, 0);
    __syncthreads();     // drains vmcnt(0): chunk 0 + A tile visible

    // A fragments, held for the whole sweep (16 frags = 64 VGPRs)
    s16x8 ahf[4][2], alf[4][2];
    #pragma unroll
    for (int i = 0; i < 4; ++i)
        #pragma unroll
        for (int s = 0; s < 2; ++s) {
            const int m = i * 16 + c16;
            const int us = ((s * 4 + g) ^ (m & 7)) * 8;
            ahf[i][s] = *(const s16x8*)&Ah[m * 64 + us];
            alf[i][s] = *(const s16x8*)&Al[m * 64 + us];
        }

    const float* vbp = vb + w * 16 + c16;
    const float* u0p = ub + (size_t)(b * N_ + n0) * H_ + w * 16 + c16;
    const float* u1p = u0p + H_;

    const int sr = c16 & 7;
    const int rbase = (w * 16 + c16) * 64;
    const int ubo0 = (g ^ sr) * 8;
    const int ubo1 = ((g + 4) ^ sr) * 8;

    f32x4 part[4] = {};

    #pragma unroll 2
    for (int c = 0; c < 16; ++c) {
        const int cur = c & 1;
        if (c < 15) STAGEW(cur ^ 1, c + 1);
        const float vbv = vbp[c * 64];
        const float uu0 = u0p[c * 64];
        const float uu1 = u1p[c * 64];
        const s16x8 bh0 = *(const s16x8*)&Wc[cur][rbase + ubo0];
        const s16x8 bh1 = *(const s16x8*)&Wc[cur][rbase + ubo1];
        #pragma unroll
        for (int i = 0; i < 4; ++i) {
            f32x4 acc = {};
            acc = MFMA(ahf[i][0], bh0, acc);
            acc = MFMA(alf[i][0], bh0, acc);
            acc = MFMA(ahf[i][1], bh1, acc);
            acc = MFMA(alf[i][1], bh1, acc);
            const float uu = (i < 2) ? uu0 : uu1;
            #pragma unroll
            for (int r = 0; r < 4; ++r)
                part[i][r] += fmaxf(acc[r] + vbv, 0.f) * uu;
        }
        __syncthreads();   // drains stage vmcnt; consume->restage ordering
    }
#undef STAGEW

    #pragma unroll
    for (int i = 0; i < 4; ++i)
        #pragma unroll
        for (int r = 0; r < 4; ++r) {
            float v = part[i][r];
            v += __shfl_xor(v, 1, 64);
            v += __shfl_xor(v, 2, 64);
            v += __shfl_xor(v, 4, 64);
            v += __shfl_xor(v, 8, 64);
            if (c16 == 0) lgp[w][i * 16 + g * 4 + r] = v;
        }
    __syncthreads();

    if (tid < 64) {
        const float tf = (float)(*tptr);
        const float lsum = lgp[0][tid] + lgp[1][tid] + lgp[2][tid] + lgp[3][tid];
        const float lv = (lsum + *lbptr) / tf;
        const int tg = tags[base_row + tid];
        sml[tid] = (tg > 0) ? lv : -1e30f;
    }
    __syncthreads();

    if (tid < 128) {
        const int nn = tid >> 6, o = tid & 63;
        const float* lr = &sml[nn * 32];
        const int uo = (o >> 3);          // 8-elem unit of column o
        const int oe = (o & 7);
        float m = -3.0e38f;
        #pragma unroll
        for (int a = 0; a < 32; ++a) m = fmaxf(m, lr[a]);
        float s = 0.f, accum = 0.f;
        #pragma unroll
        for (int a = 0; a < 32; ++a) {
            const int row = nn * 32 + a;
            const int idx = row * 64 + ((uo ^ (row & 7)) * 8 + oe);
            const float a1 =
                __uint_as_float(((unsigned)(unsigned short)Ah[idx]) << 16) +
                __uint_as_float(((unsigned)(unsigned short)Al[idx]) << 16);
            const float e = __expf(lr[a] - m);
            s += e;
            accum += e * a1;
        }
        out[(size_t)(b * N_ + n0 + nn) * O_ + o] = accum / s;
    }
}

extern "C" void kernel_launch(void* const* d_in, const int* in_sizes, int n_in,
                              void* d_out, int out_size, void* d_ws, size_t ws_size,
                              hipStream_t stream)
{
    const float* q    = (const float*)d_in[0];
    const float* att1 = (const float*)d_in[1];
    const float* obj  = (const float*)d_in[2];
    const int*   tags = (const int*)d_in[3];
    const int*   tptr = (const int*)d_in[4];
    const float* vw   = (const float*)d_in[5];
    const float* vb   = (const float*)d_in[6];
    const float* qw   = (const float*)d_in[7];
    const float* qb   = (const float*)d_in[8];
    const float* lw   = (const float*)d_in[9];
    const float* lb   = (const float*)d_in[10];
    float* out = (float*)d_out;

    float* ub   = (float*)d_ws;                         // [2048][1024] f32   8 MB
    short* Wth  = (short*)(ub + (size_t)B_ * N_ * H_);  // [16][1024][64]     2 MB
    short* objh = Wth + (size_t)B_ * H_ * O_;           // [1024][768]        1.5 MB
    short* objl = objh + (size_t)1024 * VD_;
    short* qh   = objl + (size_t)1024 * VD_;            // [2048][768]        3 MB
    short* ql   = qh + (size_t)2048 * VD_;
    short* vwh  = ql + (size_t)2048 * VD_;              // [1024][768]
    short* vwl  = vwh + (size_t)H_ * VD_;
    short* qwh  = vwl + (size_t)H_ * VD_;
    short* qwl  = qwh + (size_t)H_ * VD_;

    cvt_split<<<960, 256, 0, stream>>>(obj, q, vw, qw, objh, objl, qh, ql,
                                       vwh, vwl, qwh, qwl);
    gemm_split<<<768, 256, 0, stream>>>(objh, objl, qh, ql, vwh, vwl, qwh, qwl,
                                        qb, lw, Wth, ub);
    fused_logits<<<B_ * 64, 256, 0, stream>>>(att1, Wth, ub, vb, tags,
                                              tptr, lb, out);
}